// Round 1
// baseline (193.033 us; speedup 1.0000x reference)
//
#include <hip/hip_runtime.h>

#define BB 32
#define SS 1024
#define EE 256

// One wave per batch row: inclusive cumsum of duration[b, 0..S).
__global__ void lr_cumsum_kernel(const int* __restrict__ dur, int* __restrict__ cum) {
    const int b = blockIdx.x;
    const int lane = threadIdx.x;           // 0..63
    const int PER = SS / 64;                // 16 elements per lane
    const int base = b * SS + lane * PER;

    int vals[PER];
    int run = 0;
#pragma unroll
    for (int j = 0; j < PER; ++j) {
        run += dur[base + j];
        vals[j] = run;
    }
    // Wave-wide exclusive scan of per-lane totals (wave = 64 lanes).
    int inc = run;
    for (int d = 1; d < 64; d <<= 1) {
        int y = __shfl_up(inc, d, 64);
        if (lane >= d) inc += y;
    }
    const int off = inc - run;              // exclusive prefix for this lane
#pragma unroll
    for (int j = 0; j < PER; ++j) cum[base + j] = off + vals[j];
}

// One wave per output frame (b, t): binary search cum row, copy x row (float4).
__global__ void lr_expand_kernel(const float* __restrict__ x,
                                 const int* __restrict__ cum,
                                 float* __restrict__ out,
                                 float* __restrict__ mask,
                                 int max_mel) {
    const int b = blockIdx.y;
    const int wave = threadIdx.x >> 6;      // 4 waves per block
    const int lane = threadIdx.x & 63;
    const int t = blockIdx.x * 4 + wave;
    if (t >= max_mel) return;

    const int* crow = cum + b * SS;
    const int mel_len = crow[SS - 1];

    float4* orow = (float4*)(out + ((size_t)b * max_mel + t) * EE);

    if (t >= mel_len) {
        orow[lane] = make_float4(0.f, 0.f, 0.f, 0.f);
        if (lane == 0) mask[(size_t)b * max_mel + t] = 1.0f;
        return;
    }

    // searchsorted(crow, t, side='right'): first idx with crow[idx] > t.
    int lo = 0, hi = SS;
    while (lo < hi) {
        const int mid = (lo + hi) >> 1;
        if (crow[mid] <= t) lo = mid + 1; else hi = mid;
    }
    int idx = lo;
    if (idx > SS - 1) idx = SS - 1;

    const float4* xrow = (const float4*)(x + ((size_t)b * SS + idx) * EE);
    orow[lane] = xrow[lane];                // 64 lanes x 16 B = 1 KiB coalesced
    if (lane == 0) mask[(size_t)b * max_mel + t] = 0.0f;
}

extern "C" void kernel_launch(void* const* d_in, const int* in_sizes, int n_in,
                              void* d_out, int out_size, void* d_ws, size_t ws_size,
                              hipStream_t stream) {
    const float* x   = (const float*)d_in[0];
    const int*   dur = (const int*)d_in[1];
    float* out = (float*)d_out;

    const int max_mel = out_size / (BB * (EE + 1));   // out_size = B*max_mel*(E+1)
    float* mask = out + (size_t)BB * max_mel * EE;
    int* cum = (int*)d_ws;                             // 32*1024*4 = 128 KB scratch

    lr_cumsum_kernel<<<BB, 64, 0, stream>>>(dur, cum);

    dim3 grid((max_mel + 3) / 4, BB);
    lr_expand_kernel<<<grid, 256, 0, stream>>>(x, cum, out, mask, max_mel);
}

// Round 2
// 156.206 us; speedup vs baseline: 1.2358x; 1.2358x over previous
//
#include <hip/hip_runtime.h>

#define BB 32
#define SS 1024
#define EE 256

// One wave (one block of 64) per batch row: inclusive cumsum of duration[b,:].
// Stage through LDS so the global loads are coalesced.
__global__ void lr_cumsum_kernel(const int* __restrict__ dur, int* __restrict__ cum) {
    __shared__ int sdur[SS];
    const int b = blockIdx.x;
    const int lane = threadIdx.x;           // 0..63
    for (int j = lane; j < SS; j += 64) sdur[j] = dur[b * SS + j];
    __syncthreads();

    int vals[16];
    int run = 0;
    const int base = lane * 16;
#pragma unroll
    for (int j = 0; j < 16; ++j) { run += sdur[base + j]; vals[j] = run; }

    int inc = run;
    for (int d = 1; d < 64; d <<= 1) {
        int y = __shfl_up(inc, d, 64);
        if (lane >= d) inc += y;
    }
    const int off = inc - run;
#pragma unroll
    for (int j = 0; j < 16; ++j) cum[b * SS + base + j] = off + vals[j];
}

// Scatter: one wave per input frame (b,s). No search chain — 2 independent
// cum loads, one 1KB x-row read, duration[s] independent 1KB coalesced stores.
__global__ void lr_scatter_kernel(const float* __restrict__ x,
                                  const int* __restrict__ cum,
                                  float* __restrict__ out,
                                  float* __restrict__ mask,
                                  int max_mel) {
    const int b = blockIdx.y;
    const int wave = threadIdx.x >> 6;      // 4 waves/block
    const int lane = threadIdx.x & 63;
    const int s = blockIdx.x * 4 + wave;    // grid.x = SS/4

    const int* crow = cum + b * SS;
    const int c1 = crow[s];
    const int c0 = (s == 0) ? 0 : crow[s - 1];
    if (c1 == c0) return;                   // duration 0: nothing to emit

    const float4 v = ((const float4*)(x + ((size_t)b * SS + s) * EE))[lane];
    float4* obase = (float4*)(out + (size_t)b * max_mel * EE);
    for (int t = c0; t < c1; ++t)           // <=7 independent coalesced stores
        obase[(size_t)t * (EE / 4) + lane] = v;
    if (lane == 0)
        for (int t = c0; t < c1; ++t) mask[(size_t)b * max_mel + t] = 0.0f;
}

// Tail: zero-fill out rows and set mask=1 for t >= mel_len[b].
// Most waves early-exit after one wave-uniform broadcast load.
__global__ void lr_tail_kernel(const int* __restrict__ cum,
                               float* __restrict__ out,
                               float* __restrict__ mask,
                               int max_mel) {
    const int b = blockIdx.y;
    const int wave = threadIdx.x >> 6;
    const int lane = threadIdx.x & 63;
    const int t = blockIdx.x * 4 + wave;
    if (t >= max_mel) return;
    const int mel_len = cum[b * SS + SS - 1];
    if (t < mel_len) return;
    ((float4*)(out + ((size_t)b * max_mel + t) * EE))[lane] =
        make_float4(0.f, 0.f, 0.f, 0.f);
    if (lane == 0) mask[(size_t)b * max_mel + t] = 1.0f;
}

extern "C" void kernel_launch(void* const* d_in, const int* in_sizes, int n_in,
                              void* d_out, int out_size, void* d_ws, size_t ws_size,
                              hipStream_t stream) {
    const float* x   = (const float*)d_in[0];
    const int*   dur = (const int*)d_in[1];
    float* out = (float*)d_out;

    const int max_mel = out_size / (BB * (EE + 1));
    float* mask = out + (size_t)BB * max_mel * EE;
    int* cum = (int*)d_ws;                  // 128 KB scratch

    lr_cumsum_kernel<<<BB, 64, 0, stream>>>(dur, cum);

    dim3 sgrid(SS / 4, BB);
    lr_scatter_kernel<<<sgrid, 256, 0, stream>>>(x, cum, out, mask, max_mel);

    dim3 tgrid((max_mel + 3) / 4, BB);
    lr_tail_kernel<<<tgrid, 256, 0, stream>>>(cum, out, mask, max_mel);
}

// Round 4
// 148.001 us; speedup vs baseline: 1.3043x; 1.0554x over previous
//
#include <hip/hip_runtime.h>

#define BB 32
#define SS 1024
#define EE 256

// Native clang vector type: __builtin_nontemporal_* requires scalar/vector of
// scalars, not HIP_vector_type structs.
typedef float f4 __attribute__((ext_vector_type(4)));

// One wave (block of 64) per batch row: inclusive cumsum of duration[b,:].
__global__ void lr_cumsum_kernel(const int* __restrict__ dur, int* __restrict__ cum) {
    __shared__ int sdur[SS];
    const int b = blockIdx.x;
    const int lane = threadIdx.x;
    for (int j = lane; j < SS; j += 64) sdur[j] = dur[b * SS + j];
    __syncthreads();

    int vals[16];
    int run = 0;
    const int base = lane * 16;
#pragma unroll
    for (int j = 0; j < 16; ++j) { run += sdur[base + j]; vals[j] = run; }

    int inc = run;
    for (int d = 1; d < 64; d <<= 1) {
        int y = __shfl_up(inc, d, 64);
        if (lane >= d) inc += y;
    }
    const int off = inc - run;
#pragma unroll
    for (int j = 0; j < 16; ++j) cum[b * SS + base + j] = off + vals[j];
}

// Fused scatter + tail. One wave per index t in [0, max(SS, max_mel)).
//  - t < SS:        scatter input row s=t into out rows [cum[s-1], cum[s])
//  - t >= mel_len:  zero-fill out row t, mask=1
// Streaming traffic (x read, out write) is nontemporal: read-once/write-once
// data should not displace L2/L3 lines.
__global__ void lr_fused_kernel(const float* __restrict__ x,
                                const int* __restrict__ cum,
                                float* __restrict__ out,
                                float* __restrict__ mask,
                                int max_mel) {
    const int b = blockIdx.y;
    const int wave = threadIdx.x >> 6;      // 4 waves/block
    const int lane = threadIdx.x & 63;
    const int t = blockIdx.x * 4 + wave;

    const int* crow = cum + b * SS;
    const int mel_len = crow[SS - 1];
    f4* obase = (f4*)(out + (size_t)b * max_mel * EE);

    if (t < SS) {
        const int c1 = crow[t];
        const int c0 = (t == 0) ? 0 : crow[t - 1];
        if (c1 > c0) {
            const f4* xrow = (const f4*)(x + ((size_t)b * SS + t) * EE);
            const f4 v = __builtin_nontemporal_load(xrow + lane);
            for (int tt = c0; tt < c1; ++tt)
                __builtin_nontemporal_store(v, obase + (size_t)tt * (EE / 4) + lane);
            if (lane == 0)
                for (int tt = c0; tt < c1; ++tt)
                    mask[(size_t)b * max_mel + tt] = 0.0f;
        }
    }
    if (t >= mel_len && t < max_mel) {
        const f4 z = {0.f, 0.f, 0.f, 0.f};
        __builtin_nontemporal_store(z, obase + (size_t)t * (EE / 4) + lane);
        if (lane == 0) mask[(size_t)b * max_mel + t] = 1.0f;
    }
}

extern "C" void kernel_launch(void* const* d_in, const int* in_sizes, int n_in,
                              void* d_out, int out_size, void* d_ws, size_t ws_size,
                              hipStream_t stream) {
    const float* x   = (const float*)d_in[0];
    const int*   dur = (const int*)d_in[1];
    float* out = (float*)d_out;

    const int max_mel = out_size / (BB * (EE + 1));
    float* mask = out + (size_t)BB * max_mel * EE;
    int* cum = (int*)d_ws;                  // 128 KB scratch

    lr_cumsum_kernel<<<BB, 64, 0, stream>>>(dur, cum);

    const int span = (max_mel > SS) ? max_mel : SS;
    dim3 grid((span + 3) / 4, BB);
    lr_fused_kernel<<<grid, 256, 0, stream>>>(x, cum, out, mask, max_mel);
}